// Round 11
// baseline (417.374 us; speedup 1.0000x reference)
//
#include <hip/hip_runtime.h>
#include <hip/hip_bf16.h>
#include <math.h>

#define NN 200
#define DD 8
#define HH 128
#define NHEAD 4
#define HDIM 32
#define LL 6
#define EE 16384
#define SS 8
#define FFD 512
#define W64 256                  // EE/64 bitmap words per node column

#define WSCALE 1048576.0f        // 2^20 fixed-point scale for LDS int attention atomics
#define WNORM  (1.0f/1048576.0f)
#define RSCALE 0.17677669529663687f   // 1/sqrt(32)

// ---------------- helpers ----------------

__device__ __forceinline__ float geluf(float x) {
    return 0.5f * x * (1.0f + erff(x * 0.70710678118654752f));
}
__device__ __forceinline__ float softplusf(float x) {
    return (x > 20.0f) ? x : log1pf(expf(x));
}
__device__ __forceinline__ void ln_reduce(const float* sv, const float* sv2, float* mred, int tid) {
    if (tid < 64) {
        float s1 = sv[tid] + sv[tid + 64];
        float s2 = sv2[tid] + sv2[tid + 64];
        #pragma unroll
        for (int m = 32; m > 0; m >>= 1) {
            s1 += __shfl_xor(s1, m);
            s2 += __shfl_xor(s2, m);
        }
        if (tid == 0) { mred[0] = s1 * (1.0f / HH); mred[1] = s2 * (1.0f / HH); }
    }
}
// reduce across 8 lanes (low 3 bits)
__device__ __forceinline__ float red8(float a) {
    a += __shfl_xor(a, 1);
    a += __shfl_xor(a, 2);
    a += __shfl_xor(a, 4);
    return a;
}

// ---------------- setup ----------------

// bitmap scatter (all 512 blocks) + embed h0/hc0 (blocks < 200)
__launch_bounds__(256)
__global__ void k_bitmapEmbed(const int* __restrict__ hedges, unsigned long long* __restrict__ bmT,
                              const float* __restrict__ x, const float* __restrict__ Wi,
                              const float* __restrict__ bi, const float* __restrict__ lnig,
                              const float* __restrict__ lnib, const float* __restrict__ Wc0,
                              float* __restrict__ h, float* __restrict__ hc) {
    int a = blockIdx.x, tid = threadIdx.x;
    {
        int t = a * 256 + tid;
        int n = hedges[t];
        int e = t >> 3;
        atomicOr(&bmT[(e >> 6) * NN + n], 1ULL << (e & 63));
    }
    if (a >= NN) return;
    __shared__ float row[HH], sv[HH], sv2[HH], mred[2];
    __shared__ float psum[2][HH];
    float s = 0.0f;
    if (tid < HH) {
        s = bi[tid];
        #pragma unroll
        for (int d = 0; d < DD; ++d) s = fmaf(x[a * DD + d], Wi[d * HH + tid], s);
        sv[tid] = s; sv2[tid] = s * s;
    }
    __syncthreads();
    ln_reduce(sv, sv2, mred, tid);
    __syncthreads();
    if (tid < HH) {
        float mean = mred[0], var = mred[1] - mean * mean;
        float v = (s - mean) * rsqrtf(var + 1e-5f) * lnig[tid] + lnib[tid];
        float ge = geluf(v);
        int i2 = (tid >> 1) * 2;
        float div = expf((float)i2 * (-9.210340371976184f / 128.0f));
        float ang = (float)a * div;
        float pe = (tid & 1) ? cosf(ang) : sinf(ang);
        float hv = ge + pe;
        row[tid] = hv;
        h[a * HH + tid] = hv;
    }
    __syncthreads();
    {
        int kf = tid >> 7, j = tid & 127, k0 = kf * 64;
        float acc = 0.0f;
        #pragma unroll 8
        for (int kk = 0; kk < 64; ++kk) acc = fmaf(row[k0 + kk], Wc0[(k0 + kk) * HH + j], acc);
        psum[kf][j] = acc;
    }
    __syncthreads();
    if (tid < HH) hc[a * HH + tid] = psum[0][tid] + psum[1][tid];
}

// Per node a: float G row + member-edge list + count
__launch_bounds__(1024)
__global__ void k_prep(const unsigned long long* __restrict__ bmT,
                       float* __restrict__ Gf, int* __restrict__ lst, int* __restrict__ cntA) {
    __shared__ unsigned long long colA[W64];
    __shared__ int psG[4][256];
    __shared__ int wsum[4];
    int a = blockIdx.x, tid = threadIdx.x;
    if (tid < W64) colA[tid] = bmT[tid * NN + a];
    __syncthreads();
    {
        int q = tid >> 8, b = tid & 255;
        if (b < NN) {
            int acc = 0, w0 = q * 64;
            #pragma unroll 8
            for (int w = 0; w < 64; ++w) acc += __popcll(colA[w0 + w] & bmT[(w0 + w) * NN + b]);
            psG[q][b] = acc;
        }
    }
    unsigned long long w = 0ULL; int c = 0, incl = 0, lane = tid & 63, wid = tid >> 6;
    if (tid < W64) {
        w = colA[tid];
        c = __popcll(w);
        incl = c;
        #pragma unroll
        for (int m = 1; m < 64; m <<= 1) {
            int v = __shfl_up(incl, m);
            if (lane >= m) incl += v;
        }
        if (lane == 63) wsum[wid] = incl;
    }
    __syncthreads();
    if (tid == 0) {
        int ss = 0;
        #pragma unroll
        for (int i = 0; i < 4; ++i) { int v = wsum[i]; wsum[i] = ss; ss += v; }
        cntA[a] = ss;
    }
    if (tid < NN) Gf[a * NN + tid] = (float)(psG[0][tid] + psG[1][tid] + psG[2][tid] + psG[3][tid]);
    __syncthreads();
    if (tid < W64) {
        int base = wsum[wid] + incl - c;
        while (w) {
            int b = __ffsll((long long)w) - 1;
            w &= w - 1;
            lst[a * 1024 + base++] = tid * 64 + b;
        }
    }
}

// ---------------- layer kernels ----------------

// conv(G@hc) + LN1 + QKV. grid: 200 x 1024.
// Lane layout: j = tid>>3 (output), kq = tid&7 (split-K in-wave) -> shfl reduce, no psum/barrier.
__launch_bounds__(1024)
__global__ void k_node1(const float* __restrict__ h, const float* __restrict__ hc,
                        const float* __restrict__ Gf, const int* __restrict__ cntA,
                        const float* __restrict__ bc,
                        const float* __restrict__ Wq, const float* __restrict__ bq,
                        const float* __restrict__ Wk, const float* __restrict__ bk,
                        const float* __restrict__ Wv, const float* __restrict__ bv,
                        const float* __restrict__ n1g, const float* __restrict__ n1b,
                        float* __restrict__ h1, float* __restrict__ Qo,
                        float* __restrict__ Ko, float* __restrict__ Vo) {
    int n = blockIdx.x, tid = threadIdx.x;
    int j = tid >> 3, kq = tid & 7;
    __shared__ float Gs[NN];
    __shared__ float row[HH], sv[HH], sv2[HH], mred[2];

    // ---- register prefetch (independent loads first)
    float hcv[25];
    #pragma unroll
    for (int mm = 0; mm < 25; ++mm) hcv[mm] = hc[(mm * 8 + kq) * HH + j];
    float hval = h[n * HH + j];
    float bcv = bc[j], g1 = n1g[j], b1 = n1b[j];
    float bqv = bq[j], bkv = bk[j], bvv = bv[j];
    float cntn = fmaxf((float)cntA[n], 1.0f);
    for (int m = tid; m < NN; m += 1024) Gs[m] = Gf[n * NN + m];
    __syncthreads();

    // conv: interleaved split-K (m = mm*8+kq), in-wave reduce
    float acc = 0.0f;
    #pragma unroll
    for (int mm = 0; mm < 25; ++mm) acc = fmaf(Gs[mm * 8 + kq], hcv[mm], acc);
    acc = red8(acc);
    float val = 0.0f;
    if (kq == 0) {
        val = hval + acc / (8.0f * cntn) + bcv;
        sv[j] = val; sv2[j] = val * val;
    }
    __syncthreads();
    ln_reduce(sv, sv2, mred, tid);
    __syncthreads();
    if (kq == 0) {
        float mean = mred[0], var = mred[1] - mean * mean;
        float hv = (val - mean) * rsqrtf(var + 1e-5f) * g1 + b1;
        row[j] = hv;
        h1[n * HH + j] = hv;
    }
    __syncthreads();
    // QKV: k = kk*8+kq, chain 16, 3 accumulators, in-wave reduce
    float pq = 0.0f, pk = 0.0f, pv = 0.0f;
    #pragma unroll 4
    for (int kk = 0; kk < 16; ++kk) {
        int k = kk * 8 + kq;
        float r = row[k];
        int idx = k * HH + j;
        pq = fmaf(r, Wq[idx], pq);
        pk = fmaf(r, Wk[idx], pk);
        pv = fmaf(r, Wv[idx], pv);
    }
    pq = red8(pq); pk = red8(pk); pv = red8(pv);
    if (kq == 0) {
        Qo[n * HH + j] = bqv + pq;
        Ko[n * HH + j] = bkv + pk;
        Vo[n * HH + j] = bvv + pv;
    }
}

// attention + Wo + FFN + LN2 + next-layer hc.  grid: 200 x 1024
__launch_bounds__(1024)
__global__ void k_edgefused(const float* __restrict__ Q, const float* __restrict__ K,
                            const float* __restrict__ V, const int* __restrict__ hedges,
                            const int* __restrict__ lst, const int* __restrict__ cntA,
                            const float* __restrict__ h1,
                            const float* __restrict__ Wo, const float* __restrict__ bo,
                            const float* __restrict__ Wf1, const float* __restrict__ bf1,
                            const float* __restrict__ Wf2, const float* __restrict__ bf2,
                            const float* __restrict__ n2g, const float* __restrict__ n2b,
                            const float* __restrict__ WcN,
                            float* __restrict__ h, float* __restrict__ hc) {
    __shared__ float Ts[NHEAD * NN];
    __shared__ int   Wrow[NHEAD * NN];
    __shared__ float ts[FFD];
    __shared__ float sv[HH], sv2[HH], mred[2];
    __shared__ float aggs[HH], h2s[HH], rowN[HH];

    int a = blockIdx.x, tid = threadIdx.x;
    int j = tid >> 3, kq = tid & 7;
    int cnt = cntA[a];
    float cntn = fmaxf((float)cnt, 1.0f);
    int ntask = cnt * NHEAD;
    const int* lstA = lst + a * 1024;

    // ---- register prefetch
    float h1v = h1[a * HH + j], bov = bo[j], bf2v = bf2[j], n2gv = n2g[j], n2bv = n2b[j];
    float bf1v = bf1[tid >> 1];
    int4 pe0[4], pe1[4];
    #pragma unroll
    for (int it = 0; it < 4; ++it) {
        int t = tid + it * 1024;
        pe0[it] = make_int4(0, 0, 0, 0); pe1[it] = make_int4(0, 0, 0, 0);
        if (t < ntask) {
            int e = lstA[t >> 2];
            pe0[it] = ((const int4*)hedges)[e * 2];
            pe1[it] = ((const int4*)hedges)[e * 2 + 1];
        }
    }
    int lb = tid & 255, lh = tid >> 8;
    float4 kv[8];
    if (lb < NN) {
        const float4* kp4 = (const float4*)(K + lb * HH + lh * HDIM);
        #pragma unroll
        for (int u = 0; u < 8; ++u) kv[u] = kp4[u];
    }
    if (tid < NHEAD * NN) Wrow[tid] = 0;

    // logits Ts[h][b] = (q_a[h].k_b[h]) * RSCALE  (Q read direct — one L1-hot row)
    if (lb < NN) {
        const float4* qp4 = (const float4*)(Q + a * HH + lh * HDIM);
        float acc = 0.0f;
        #pragma unroll
        for (int u = 0; u < 8; ++u) {
            float4 qv = qp4[u];
            acc += qv.x * kv[u].x + qv.y * kv[u].y + qv.z * kv[u].z + qv.w * kv[u].w;
        }
        Ts[lh * NN + lb] = acc * RSCALE;
    }
    __syncthreads();   // Ts + Wrow-zero ready

    // phase A: per (member-edge, head) softmax -> LDS int scatter
    #pragma unroll
    for (int it = 0; it < 4; ++it) {
        int t = tid + it * 1024;
        if (t < ntask) {
            int hh = t & 3;
            int4 e0 = pe0[it], e1 = pe1[it];
            const float* Tr = Ts + hh * NN;
            float l0 = Tr[e0.x], l1 = Tr[e0.y], l2 = Tr[e0.z], l3 = Tr[e0.w];
            float l4 = Tr[e1.x], l5 = Tr[e1.y], l6 = Tr[e1.z], l7 = Tr[e1.w];
            float mx = fmaxf(fmaxf(fmaxf(l0, l1), fmaxf(l2, l3)),
                             fmaxf(fmaxf(l4, l5), fmaxf(l6, l7)));
            l0 = __expf(l0 - mx); l1 = __expf(l1 - mx); l2 = __expf(l2 - mx); l3 = __expf(l3 - mx);
            l4 = __expf(l4 - mx); l5 = __expf(l5 - mx); l6 = __expf(l6 - mx); l7 = __expf(l7 - mx);
            float inv = WSCALE / (l0 + l1 + l2 + l3 + l4 + l5 + l6 + l7);
            int* Wr = Wrow + hh * NN;
            atomicAdd(&Wr[e0.x], __float2int_rn(l0 * inv));
            atomicAdd(&Wr[e0.y], __float2int_rn(l1 * inv));
            atomicAdd(&Wr[e0.z], __float2int_rn(l2 * inv));
            atomicAdd(&Wr[e0.w], __float2int_rn(l3 * inv));
            atomicAdd(&Wr[e1.x], __float2int_rn(l4 * inv));
            atomicAdd(&Wr[e1.y], __float2int_rn(l5 * inv));
            atomicAdd(&Wr[e1.z], __float2int_rn(l6 * inv));
            atomicAdd(&Wr[e1.w], __float2int_rn(l7 * inv));
        }
    }
    __syncthreads();

    // phase B: agg = Wrow@V, interleaved split (b = bb*8+kq), in-wave reduce
    {
        int hh = j >> 5;
        float acc = 0.0f;
        #pragma unroll 5
        for (int bb = 0; bb < 25; ++bb) {
            int b = bb * 8 + kq;
            acc = fmaf((float)Wrow[hh * NN + b], V[b * HH + j], acc);
        }
        acc = red8(acc);
        if (kq == 0) aggs[j] = acc * WNORM / cntn;
    }
    __syncthreads();
    // Wo GEMV -> h2
    {
        float p = 0.0f;
        #pragma unroll 8
        for (int kk = 0; kk < 16; ++kk) {
            int k = kk * 8 + kq;
            p = fmaf(aggs[k], Wo[k * HH + j], p);
        }
        p = red8(p);
        if (kq == 0) h2s[j] = h1v + bov + p;
    }
    __syncthreads();
    // FFN1: f = tid>>1, 2-way split (k = kk*2+kf), shfl pair reduce
    {
        int f = tid >> 1, kf = tid & 1;
        float tv = 0.0f;
        #pragma unroll 8
        for (int kk = 0; kk < 64; ++kk) {
            int k = kk * 2 + kf;
            tv = fmaf(h2s[k], Wf1[k * FFD + f], tv);
        }
        tv += __shfl_xor(tv, 1);
        if (kf == 0) ts[f] = geluf(bf1v + tv);
    }
    __syncthreads();
    // FFN2: f = ff*8+kq, chain 64, in-wave reduce
    float o = 0.0f;
    {
        float p = 0.0f;
        #pragma unroll 8
        for (int ff = 0; ff < 64; ++ff) {
            int f = ff * 8 + kq;
            p = fmaf(ts[f], Wf2[f * HH + j], p);
        }
        p = red8(p);
        if (kq == 0) {
            o = h2s[j] + bf2v + p;
            sv[j] = o; sv2[j] = o * o;
        }
    }
    __syncthreads();
    ln_reduce(sv, sv2, mred, tid);
    __syncthreads();
    if (kq == 0) {
        float mean = mred[0], var = mred[1] - mean * mean;
        float hv = (o - mean) * rsqrtf(var + 1e-5f) * n2gv + n2bv;
        rowN[j] = hv;
        h[a * HH + j] = hv;
    }
    __syncthreads();
    if (WcN) {
        float p = 0.0f;
        #pragma unroll 8
        for (int kk = 0; kk < 16; ++kk) {
            int k = kk * 8 + kq;
            p = fmaf(rowN[k], WcN[k * HH + j], p);
        }
        p = red8(p);
        if (kq == 0) hc[a * HH + j] = p;
    }
}

// Pool + heads + emb, 4 blocks x 512
__launch_bounds__(512)
__global__ void k_final4(const float* __restrict__ h,
                         const float* __restrict__ Wh1, const float* __restrict__ bh1,
                         const float* __restrict__ Wh2, const float* __restrict__ bh2,
                         const float* __restrict__ Wh3, const float* __restrict__ bh3,
                         const float* __restrict__ We, const float* __restrict__ be,
                         float* __restrict__ out) {
    __shared__ float gs[384];
    __shared__ float pm[4][HH], px[4][HH];
    __shared__ float psum[4][HH];
    __shared__ float t1s[HH];
    __shared__ float t2s[64];
    int tid = threadIdx.x, j = tid & 127, kq = tid >> 7, kb = blockIdx.x;
    {
        float sm = 0.0f, mx = -3.4e38f;
        for (int r = 0; r < 50; ++r) {
            float v = h[(kq * 50 + r) * HH + j];
            sm += v; mx = fmaxf(mx, v);
        }
        pm[kq][j] = sm; px[kq][j] = mx;
    }
    __syncthreads();
    if (tid < HH) {
        float s = pm[0][j] + pm[1][j] + pm[2][j] + pm[3][j];
        float m = fmaxf(fmaxf(px[0][j], px[1][j]), fmaxf(px[2][j], px[3][j]));
        gs[j] = s * (1.0f / NN); gs[HH + j] = m; gs[2 * HH + j] = s;
    }
    __syncthreads();
    if (kb < 3) {
        float p = 0.0f;
        int i0 = kq * 96;
        #pragma unroll 8
        for (int ii = 0; ii < 96; ++ii) p = fmaf(gs[i0 + ii], Wh1[kb * 49152 + (i0 + ii) * 128 + j], p);
        psum[kq][j] = p;
        __syncthreads();
        if (tid < HH) t1s[j] = geluf(bh1[kb * 128 + j] + psum[0][j] + psum[1][j] + psum[2][j] + psum[3][j]);
        __syncthreads();
        if (tid < 256) {
            int o = tid & 63, sc = tid >> 6;
            float p2 = 0.0f;
            int i0b = sc * 32;
            #pragma unroll 8
            for (int ii = 0; ii < 32; ++ii) p2 = fmaf(t1s[i0b + ii], Wh2[kb * 8192 + (i0b + ii) * 64 + o], p2);
            psum[sc][o] = p2;
        }
        __syncthreads();
        if (tid < 64) t2s[tid] = geluf(bh2[kb * 64 + tid] + psum[0][tid] + psum[1][tid] + psum[2][tid] + psum[3][tid]);
        __syncthreads();
        if (tid < 64) {
            float v = t2s[tid] * Wh3[kb * 64 + tid];
            #pragma unroll
            for (int m = 32; m > 0; m >>= 1) v += __shfl_xor(v, m);
            if (tid == 0) {
                float acc = v + bh3[kb];
                float r;
                if (kb == 0)      r = softplusf(acc) + 1.0f;
                else if (kb == 1) r = 1.0f / (1.0f + expf(-acc));
                else              r = softplusf(acc);
                out[kb] = r;
            }
        }
    } else {
        float p = 0.0f;
        int i0 = kq * 96;
        #pragma unroll 8
        for (int ii = 0; ii < 96; ++ii) p = fmaf(gs[i0 + ii], We[(i0 + ii) * 128 + j], p);
        psum[kq][j] = p;
        __syncthreads();
        if (tid < HH) out[3 + j] = be[j] + psum[0][j] + psum[1][j] + psum[2][j] + psum[3][j];
    }
}

// ---------------- launch ----------------

extern "C" void kernel_launch(void* const* d_in, const int* in_sizes, int n_in,
                              void* d_out, int out_size, void* d_ws, size_t ws_size,
                              hipStream_t stream) {
    const float* x      = (const float*)d_in[0];
    const int*   hedges = (const int*)d_in[1];
    const float* Wi     = (const float*)d_in[2];
    const float* bi     = (const float*)d_in[3];
    const float* lnig   = (const float*)d_in[4];
    const float* lnib   = (const float*)d_in[5];
    const float* Wc     = (const float*)d_in[6];
    const float* bc     = (const float*)d_in[7];
    const float* Wq     = (const float*)d_in[8];
    const float* bq     = (const float*)d_in[9];
    const float* Wk     = (const float*)d_in[10];
    const float* bk     = (const float*)d_in[11];
    const float* Wv     = (const float*)d_in[12];
    const float* bv     = (const float*)d_in[13];
    const float* Wo     = (const float*)d_in[14];
    const float* bo     = (const float*)d_in[15];
    const float* n1g    = (const float*)d_in[16];
    const float* n1b    = (const float*)d_in[17];
    const float* n2g    = (const float*)d_in[18];
    const float* n2b    = (const float*)d_in[19];
    const float* Wf1    = (const float*)d_in[20];
    const float* bf1    = (const float*)d_in[21];
    const float* Wf2    = (const float*)d_in[22];
    const float* bf2    = (const float*)d_in[23];
    const float* Wh1    = (const float*)d_in[24];
    const float* bh1    = (const float*)d_in[25];
    const float* Wh2    = (const float*)d_in[26];
    const float* bh2    = (const float*)d_in[27];
    const float* Wh3    = (const float*)d_in[28];
    const float* bh3    = (const float*)d_in[29];
    const float* We     = (const float*)d_in[30];
    const float* be     = (const float*)d_in[31];

    float* ws = (float*)d_ws;
    float* h    = ws;                          // 25600
    float* h1   = ws + 25600;                  // 25600
    float* hc   = ws + 51200;                  // 25600
    float* Q    = ws + 76800;                  // 25600
    float* K    = ws + 102400;                 // 25600
    float* V    = ws + 128000;                 // 25600
    float* Gf   = ws + 153600;                 // 40000
    unsigned long long* bmT = (unsigned long long*)(ws + 193600);  // 51200 u64
    int*   lst  = (int*)(ws + 296000);         // 200*1024 ints
    int*   cntA = (int*)(ws + 500800);         // 256 ints

    hipMemsetAsync(bmT, 0, (size_t)W64 * NN * sizeof(unsigned long long), stream);
    k_bitmapEmbed<<<512, 256, 0, stream>>>(hedges, bmT, x, Wi, bi, lnig, lnib, Wc, h, hc);
    k_prep<<<NN, 1024, 0, stream>>>(bmT, Gf, lst, cntA);

    for (int l = 0; l < LL; ++l) {
        k_node1<<<NN, 1024, 0, stream>>>(h, hc, Gf, cntA,
            bc + l * HH,
            Wq + l * HH * HH, bq + l * HH,
            Wk + l * HH * HH, bk + l * HH,
            Wv + l * HH * HH, bv + l * HH,
            n1g + l * HH, n1b + l * HH,
            h1, Q, K, V);
        const float* WcN = (l + 1 < LL) ? (Wc + (l + 1) * HH * HH) : nullptr;
        k_edgefused<<<NN, 1024, 0, stream>>>(Q, K, V, hedges, lst, cntA, h1,
            Wo + l * HH * HH, bo + l * HH,
            Wf1 + l * HH * FFD, bf1 + l * FFD,
            Wf2 + l * FFD * HH, bf2 + l * HH,
            n2g + l * HH, n2b + l * HH,
            WcN, h, hc);
    }

    k_final4<<<4, 512, 0, stream>>>(h, Wh1, bh1, Wh2, bh2, Wh3, bh3, We, be, (float*)d_out);
}

// Round 12
// 214.330 us; speedup vs baseline: 1.9473x; 1.9473x over previous
//
#include <hip/hip_runtime.h>
#include <hip/hip_bf16.h>
#include <math.h>

#define NN 200
#define DD 8
#define HH 128
#define NHEAD 4
#define HDIM 32
#define LL 6
#define EE 16384
#define SS 8
#define FFD 512
#define W64 256                  // EE/64 bitmap words per node column

#define WSCALE 1048576.0f        // 2^20 fixed-point scale for LDS int attention atomics
#define WNORM  (1.0f/1048576.0f)
#define RSCALE 0.17677669529663687f   // 1/sqrt(32)

// bf16 weight pool offsets (ushort units)
#define OWC  0
#define OWQ  98304
#define OWK  196608
#define OWV  294912
#define OWO  393216
#define OWF1 491520
#define OWF2 884736
#define WTOT 1277952

// ---------------- helpers ----------------

__device__ __forceinline__ float geluf(float x) {
    return 0.5f * x * (1.0f + erff(x * 0.70710678118654752f));
}
__device__ __forceinline__ float softplusf(float x) {
    return (x > 20.0f) ? x : log1pf(expf(x));
}
__device__ __forceinline__ float bf2f(unsigned short u) {
    return __uint_as_float(((unsigned int)u) << 16);
}
__device__ __forceinline__ unsigned short f2bf(float x) {
    unsigned int u = __float_as_uint(x);
    return (unsigned short)((u + 0x7FFFu + ((u >> 16) & 1u)) >> 16);
}
__device__ __forceinline__ void ln_reduce(const float* sv, const float* sv2, float* mred, int tid) {
    if (tid < 64) {
        float s1 = sv[tid] + sv[tid + 64];
        float s2 = sv2[tid] + sv2[tid + 64];
        #pragma unroll
        for (int m = 32; m > 0; m >>= 1) {
            s1 += __shfl_xor(s1, m);
            s2 += __shfl_xor(s2, m);
        }
        if (tid == 0) { mred[0] = s1 * (1.0f / HH); mred[1] = s2 * (1.0f / HH); }
    }
}

// ---------------- setup ----------------

// bitmap scatter (all 512 blocks); blocks <200: embed h0/hc0; blocks >=200: bf16 weight convert
__launch_bounds__(256)
__global__ void k_bitmapEmbed(const int* __restrict__ hedges, unsigned long long* __restrict__ bmT,
                              const float* __restrict__ x, const float* __restrict__ Wi,
                              const float* __restrict__ bi, const float* __restrict__ lnig,
                              const float* __restrict__ lnib,
                              const float* __restrict__ Wc, const float* __restrict__ Wq,
                              const float* __restrict__ Wk, const float* __restrict__ Wv,
                              const float* __restrict__ Wo, const float* __restrict__ Wf1,
                              const float* __restrict__ Wf2, unsigned short* __restrict__ bw,
                              float* __restrict__ h, float* __restrict__ hc) {
    int a = blockIdx.x, tid = threadIdx.x;
    {
        int t = a * 256 + tid;
        int n = hedges[t];
        int e = t >> 3;
        atomicOr(&bmT[(e >> 6) * NN + n], 1ULL << (e & 63));
    }
    if (a >= NN) {
        // idle blocks: convert weights to bf16 (grid-stride)
        for (int i = (a - NN) * 256 + tid; i < WTOT; i += (512 - NN) * 256) {
            float v;
            if (i < OWQ)       v = Wc[i];
            else if (i < OWK)  v = Wq[i - OWQ];
            else if (i < OWV)  v = Wk[i - OWK];
            else if (i < OWO)  v = Wv[i - OWV];
            else if (i < OWF1) v = Wo[i - OWO];
            else if (i < OWF2) v = Wf1[i - OWF1];
            else               v = Wf2[i - OWF2];
            bw[i] = f2bf(v);
        }
        return;
    }
    __shared__ float row[HH], sv[HH], sv2[HH], mred[2];
    __shared__ float psum[2][HH];
    float s = 0.0f;
    if (tid < HH) {
        s = bi[tid];
        #pragma unroll
        for (int d = 0; d < DD; ++d) s = fmaf(x[a * DD + d], Wi[d * HH + tid], s);
        sv[tid] = s; sv2[tid] = s * s;
    }
    __syncthreads();
    ln_reduce(sv, sv2, mred, tid);
    __syncthreads();
    if (tid < HH) {
        float mean = mred[0], var = mred[1] - mean * mean;
        float v = (s - mean) * rsqrtf(var + 1e-5f) * lnig[tid] + lnib[tid];
        float ge = geluf(v);
        int i2 = (tid >> 1) * 2;
        float div = expf((float)i2 * (-9.210340371976184f / 128.0f));
        float ang = (float)a * div;
        float pe = (tid & 1) ? cosf(ang) : sinf(ang);
        float hv = ge + pe;
        row[tid] = hv;
        h[a * HH + tid] = hv;
    }
    __syncthreads();
    {   // hc0 = row @ Wc[0] (fp32 source — bw not yet ordered)
        int kf = tid >> 7, j = tid & 127, k0 = kf * 64;
        float acc = 0.0f;
        #pragma unroll 8
        for (int kk = 0; kk < 64; ++kk) acc = fmaf(row[k0 + kk], Wc[(k0 + kk) * HH + j], acc);
        psum[kf][j] = acc;
    }
    __syncthreads();
    if (tid < HH) hc[a * HH + tid] = psum[0][tid] + psum[1][tid];
}

// Per node a: float G row + member-edge list + count
__launch_bounds__(1024)
__global__ void k_prep(const unsigned long long* __restrict__ bmT,
                       float* __restrict__ Gf, int* __restrict__ lst, int* __restrict__ cntA) {
    __shared__ unsigned long long colA[W64];
    __shared__ int psG[4][256];
    __shared__ int wsum[4];
    int a = blockIdx.x, tid = threadIdx.x;
    if (tid < W64) colA[tid] = bmT[tid * NN + a];
    __syncthreads();
    {
        int q = tid >> 8, b = tid & 255;
        if (b < NN) {
            int acc = 0, w0 = q * 64;
            #pragma unroll 8
            for (int w = 0; w < 64; ++w) acc += __popcll(colA[w0 + w] & bmT[(w0 + w) * NN + b]);
            psG[q][b] = acc;
        }
    }
    unsigned long long w = 0ULL; int c = 0, incl = 0, lane = tid & 63, wid = tid >> 6;
    if (tid < W64) {
        w = colA[tid];
        c = __popcll(w);
        incl = c;
        #pragma unroll
        for (int m = 1; m < 64; m <<= 1) {
            int v = __shfl_up(incl, m);
            if (lane >= m) incl += v;
        }
        if (lane == 63) wsum[wid] = incl;
    }
    __syncthreads();
    if (tid == 0) {
        int ss = 0;
        #pragma unroll
        for (int i = 0; i < 4; ++i) { int v = wsum[i]; wsum[i] = ss; ss += v; }
        cntA[a] = ss;
    }
    if (tid < NN) Gf[a * NN + tid] = (float)(psG[0][tid] + psG[1][tid] + psG[2][tid] + psG[3][tid]);
    __syncthreads();
    if (tid < W64) {
        int base = wsum[wid] + incl - c;
        while (w) {
            int b = __ffsll((long long)w) - 1;
            w &= w - 1;
            lst[a * 1024 + base++] = tid * 64 + b;
        }
    }
}

// ---------------- layer kernels ----------------

// conv(G@hc) + LN1 + QKV.  grid: 200 x 1024 (R8 structure; bf16 QKV weights)
__launch_bounds__(1024)
__global__ void k_node1(const float* __restrict__ h, const float* __restrict__ hc,
                        const float* __restrict__ Gf, const int* __restrict__ cntA,
                        const float* __restrict__ bc,
                        const unsigned short* __restrict__ bWq, const float* __restrict__ bq,
                        const unsigned short* __restrict__ bWk, const float* __restrict__ bk,
                        const unsigned short* __restrict__ bWv, const float* __restrict__ bv,
                        const float* __restrict__ n1g, const float* __restrict__ n1b,
                        float* __restrict__ h1, float* __restrict__ Qo,
                        float* __restrict__ Ko, float* __restrict__ Vo) {
    int n = blockIdx.x, tid = threadIdx.x;
    int j = tid & 127, kq = tid >> 7;
    __shared__ float Gs[NN];
    __shared__ float row[HH], sv[HH], sv2[HH], mred[2];
    __shared__ float psA[8][HH], psB[8][HH], psC[8][HH];

    // ---- register prefetch
    float hcv[25];
    {
        int m0 = kq * 25;
        #pragma unroll
        for (int mm = 0; mm < 25; ++mm) hcv[mm] = hc[(m0 + mm) * HH + j];
    }
    float hval = 0.0f, bcv = 0.0f, g1 = 0.0f, b1 = 0.0f;
    if (tid < HH) { hval = h[n * HH + tid]; bcv = bc[tid]; g1 = n1g[tid]; b1 = n1b[tid]; }
    float biasv = 0.0f;
    if (tid < 384) {
        int wh = tid >> 7;
        biasv = (wh == 0) ? bq[j] : (wh == 1) ? bk[j] : bv[j];
    }
    float cntn = fmaxf((float)cntA[n], 1.0f);
    if (tid < NN) Gs[tid] = Gf[n * NN + tid];
    __syncthreads();

    // conv: 8 kq x 25 rows
    {
        float p = 0.0f; int m0 = kq * 25;
        #pragma unroll
        for (int mm = 0; mm < 25; ++mm) p = fmaf(Gs[m0 + mm], hcv[mm], p);
        psA[kq][j] = p;
    }
    __syncthreads();
    float val = 0.0f;
    if (tid < HH) {
        float acc = psA[0][tid] + psA[1][tid] + psA[2][tid] + psA[3][tid]
                  + psA[4][tid] + psA[5][tid] + psA[6][tid] + psA[7][tid];
        val = hval + acc / (8.0f * cntn) + bcv;
        sv[tid] = val; sv2[tid] = val * val;
    }
    __syncthreads();
    ln_reduce(sv, sv2, mred, tid);
    __syncthreads();
    if (tid < HH) {
        float mean = mred[0], var = mred[1] - mean * mean;
        float hv = (val - mean) * rsqrtf(var + 1e-5f) * g1 + b1;
        row[tid] = hv;
        h1[n * HH + tid] = hv;
    }
    __syncthreads();
    // QKV: 8 kq x 16 k, bf16 weights
    {
        float pq = 0.0f, pk = 0.0f, pv = 0.0f; int k0 = kq * 16;
        #pragma unroll 4
        for (int kk = 0; kk < 16; ++kk) {
            float r = row[k0 + kk]; int idx = (k0 + kk) * HH + j;
            pq = fmaf(r, bf2f(bWq[idx]), pq);
            pk = fmaf(r, bf2f(bWk[idx]), pk);
            pv = fmaf(r, bf2f(bWv[idx]), pv);
        }
        psA[kq][j] = pq; psB[kq][j] = pk; psC[kq][j] = pv;
    }
    __syncthreads();
    if (tid < 384) {
        int wh = tid >> 7;
        const float (*pf)[HH] = (wh == 0) ? psA : (wh == 1) ? psB : psC;
        float acc = pf[0][j] + pf[1][j] + pf[2][j] + pf[3][j]
                  + pf[4][j] + pf[5][j] + pf[6][j] + pf[7][j];
        float o = biasv + acc;
        if (wh == 0)      Qo[n * HH + j] = o;
        else if (wh == 1) Ko[n * HH + j] = o;
        else              Vo[n * HH + j] = o;
    }
}

// attention + Wo + FFN + LN2 + next-layer hc.  grid: 200 x 1024
__launch_bounds__(1024)
__global__ void k_edgefused(const float* __restrict__ Q, const float* __restrict__ K,
                            const float* __restrict__ V, const int* __restrict__ hedges,
                            const int* __restrict__ lst, const int* __restrict__ cntA,
                            const float* __restrict__ h1,
                            const unsigned short* __restrict__ bWo, const float* __restrict__ bo,
                            const unsigned short* __restrict__ bWf1, const float* __restrict__ bf1,
                            const unsigned short* __restrict__ bWf2, const float* __restrict__ bf2,
                            const float* __restrict__ n2g, const float* __restrict__ n2b,
                            const unsigned short* __restrict__ bWcN,
                            float* __restrict__ h, float* __restrict__ hc) {
    __shared__ float Ts[NHEAD * NN];
    __shared__ int   Wrow[NHEAD * NN];
    __shared__ float psum[8][HH];
    __shared__ float ts[FFD];
    __shared__ float sv[HH], sv2[HH], mred[2];
    __shared__ float aggs[HH], h2s[HH], rowN[HH];

    int a = blockIdx.x, tid = threadIdx.x;
    int j = tid & 127, kq = tid >> 7;
    int cnt = cntA[a];
    float cntn = fmaxf((float)cnt, 1.0f);
    int ntask = cnt * NHEAD;
    const int* lstA = lst + a * 1024;

    // ---- register prefetch
    float h1v = 0.0f, bov = 0.0f, bf2v = 0.0f, n2gv = 0.0f, n2bv = 0.0f;
    if (tid < HH) {
        h1v = h1[a * HH + tid]; bov = bo[tid];
        bf2v = bf2[tid]; n2gv = n2g[tid]; n2bv = n2b[tid];
    }
    float bf1v = bf1[tid >> 1];
    // V rows for phase B (independent of everything)
    float vv[25];
    {
        int b0 = kq * 25;
        #pragma unroll
        for (int bb = 0; bb < 25; ++bb) vv[bb] = V[(b0 + bb) * HH + j];
    }
    int4 pe0[4], pe1[4];
    #pragma unroll
    for (int it = 0; it < 4; ++it) {
        int t = tid + it * 1024;
        pe0[it] = make_int4(0, 0, 0, 0); pe1[it] = make_int4(0, 0, 0, 0);
        if (t < ntask) {
            int e = lstA[t >> 2];
            pe0[it] = ((const int4*)hedges)[e * 2];
            pe1[it] = ((const int4*)hedges)[e * 2 + 1];
        }
    }
    int lb = tid & 255, lh = tid >> 8;
    float4 kv[8];
    if (lb < NN) {
        const float4* kp4 = (const float4*)(K + lb * HH + lh * HDIM);
        #pragma unroll
        for (int u = 0; u < 8; ++u) kv[u] = kp4[u];
    }
    if (tid < NHEAD * NN) Wrow[tid] = 0;

    // logits Ts[h][b] = (q_a[h].k_b[h]) * RSCALE   (Q read direct: one L1-hot row)
    if (lb < NN) {
        const float4* qp4 = (const float4*)(Q + a * HH + lh * HDIM);
        float acc = 0.0f;
        #pragma unroll
        for (int u = 0; u < 8; ++u) {
            float4 qv = qp4[u];
            acc += qv.x * kv[u].x + qv.y * kv[u].y + qv.z * kv[u].z + qv.w * kv[u].w;
        }
        Ts[lh * NN + lb] = acc * RSCALE;
    }
    __syncthreads();   // Ts + Wrow-zero ready

    // phase A: per (member-edge, head) softmax -> LDS int scatter
    #pragma unroll
    for (int it = 0; it < 4; ++it) {
        int t = tid + it * 1024;
        if (t < ntask) {
            int hh = t & 3;
            int4 e0 = pe0[it], e1 = pe1[it];
            const float* Tr = Ts + hh * NN;
            float l0 = Tr[e0.x], l1 = Tr[e0.y], l2 = Tr[e0.z], l3 = Tr[e0.w];
            float l4 = Tr[e1.x], l5 = Tr[e1.y], l6 = Tr[e1.z], l7 = Tr[e1.w];
            float mx = fmaxf(fmaxf(fmaxf(l0, l1), fmaxf(l2, l3)),
                             fmaxf(fmaxf(l4, l5), fmaxf(l6, l7)));
            l0 = __expf(l0 - mx); l1 = __expf(l1 - mx); l2 = __expf(l2 - mx); l3 = __expf(l3 - mx);
            l4 = __expf(l4 - mx); l5 = __expf(l5 - mx); l6 = __expf(l6 - mx); l7 = __expf(l7 - mx);
            float inv = WSCALE / (l0 + l1 + l2 + l3 + l4 + l5 + l6 + l7);
            int* Wr = Wrow + hh * NN;
            atomicAdd(&Wr[e0.x], __float2int_rn(l0 * inv));
            atomicAdd(&Wr[e0.y], __float2int_rn(l1 * inv));
            atomicAdd(&Wr[e0.z], __float2int_rn(l2 * inv));
            atomicAdd(&Wr[e0.w], __float2int_rn(l3 * inv));
            atomicAdd(&Wr[e1.x], __float2int_rn(l4 * inv));
            atomicAdd(&Wr[e1.y], __float2int_rn(l5 * inv));
            atomicAdd(&Wr[e1.z], __float2int_rn(l6 * inv));
            atomicAdd(&Wr[e1.w], __float2int_rn(l7 * inv));
        }
    }
    __syncthreads();

    // phase B: agg = Wrow@V from prefetched vv, 8 kq x 25 b  (j = hh*32+d)
    {
        int hh = (tid >> 5) & 3;
        float acc = 0.0f; int b0 = kq * 25;
        #pragma unroll
        for (int bb = 0; bb < 25; ++bb)
            acc = fmaf((float)Wrow[hh * NN + b0 + bb], vv[bb], acc);
        psum[kq][j] = acc;
    }
    __syncthreads();
    if (tid < HH) {
        float acc = psum[0][tid] + psum[1][tid] + psum[2][tid] + psum[3][tid]
                  + psum[4][tid] + psum[5][tid] + psum[6][tid] + psum[7][tid];
        aggs[tid] = acc * WNORM / cntn;
    }
    __syncthreads();
    // Wo GEMV: 8 kq x 16, bf16
    {
        float p = 0.0f; int k0 = kq * 16;
        #pragma unroll 8
        for (int kk = 0; kk < 16; ++kk) p = fmaf(aggs[k0 + kk], bf2f(bWo[(k0 + kk) * HH + j]), p);
        psum[kq][j] = p;
    }
    __syncthreads();
    if (tid < HH) {
        float acc = psum[0][tid] + psum[1][tid] + psum[2][tid] + psum[3][tid]
                  + psum[4][tid] + psum[5][tid] + psum[6][tid] + psum[7][tid];
        h2s[tid] = h1v + bov + acc;
    }
    __syncthreads();
    // FFN1: f = tid>>1, pair split-K (k = kk*2+kf), in-wave shuffle reduce
    {
        int f = tid >> 1, kf = tid & 1;
        float tv = 0.0f;
        #pragma unroll 8
        for (int kk = 0; kk < 64; ++kk) {
            int k = kk * 2 + kf;
            tv = fmaf(h2s[k], bf2f(bWf1[k * FFD + f]), tv);
        }
        tv += __shfl_xor(tv, 1);
        if (kf == 0) ts[f] = geluf(bf1v + tv);
    }
    __syncthreads();
    // FFN2: 8 kq x 64, bf16
    {
        float p = 0.0f; int f0 = kq * 64;
        #pragma unroll 8
        for (int ff = 0; ff < 64; ++ff) p = fmaf(ts[f0 + ff], bf2f(bWf2[(f0 + ff) * HH + j]), p);
        psum[kq][j] = p;
    }
    __syncthreads();
    float o = 0.0f;
    if (tid < HH) {
        float acc = psum[0][tid] + psum[1][tid] + psum[2][tid] + psum[3][tid]
                  + psum[4][tid] + psum[5][tid] + psum[6][tid] + psum[7][tid];
        o = h2s[tid] + bf2v + acc;
        sv[tid] = o; sv2[tid] = o * o;
    }
    __syncthreads();
    ln_reduce(sv, sv2, mred, tid);
    __syncthreads();
    if (tid < HH) {
        float mean = mred[0], var = mred[1] - mean * mean;
        float hv = (o - mean) * rsqrtf(var + 1e-5f) * n2gv + n2bv;
        rowN[tid] = hv;
        h[a * HH + tid] = hv;
    }
    __syncthreads();
    if (bWcN) {
        float p = 0.0f; int k0 = kq * 16;
        #pragma unroll 8
        for (int kk = 0; kk < 16; ++kk) p = fmaf(rowN[k0 + kk], bf2f(bWcN[(k0 + kk) * HH + j]), p);
        psum[kq][j] = p;
        __syncthreads();
        if (tid < HH) {
            float acc = psum[0][tid] + psum[1][tid] + psum[2][tid] + psum[3][tid]
                      + psum[4][tid] + psum[5][tid] + psum[6][tid] + psum[7][tid];
            hc[a * HH + tid] = acc;
        }
    }
}

// Pool + heads + emb, 4 blocks x 512
__launch_bounds__(512)
__global__ void k_final4(const float* __restrict__ h,
                         const float* __restrict__ Wh1, const float* __restrict__ bh1,
                         const float* __restrict__ Wh2, const float* __restrict__ bh2,
                         const float* __restrict__ Wh3, const float* __restrict__ bh3,
                         const float* __restrict__ We, const float* __restrict__ be,
                         float* __restrict__ out) {
    __shared__ float gs[384];
    __shared__ float pm[4][HH], px[4][HH];
    __shared__ float psum[4][HH];
    __shared__ float t1s[HH];
    __shared__ float t2s[64];
    int tid = threadIdx.x, j = tid & 127, kq = tid >> 7, kb = blockIdx.x;
    {
        float sm = 0.0f, mx = -3.4e38f;
        for (int r = 0; r < 50; ++r) {
            float v = h[(kq * 50 + r) * HH + j];
            sm += v; mx = fmaxf(mx, v);
        }
        pm[kq][j] = sm; px[kq][j] = mx;
    }
    __syncthreads();
    if (tid < HH) {
        float s = pm[0][j] + pm[1][j] + pm[2][j] + pm[3][j];
        float m = fmaxf(fmaxf(px[0][j], px[1][j]), fmaxf(px[2][j], px[3][j]));
        gs[j] = s * (1.0f / NN); gs[HH + j] = m; gs[2 * HH + j] = s;
    }
    __syncthreads();
    if (kb < 3) {
        float p = 0.0f;
        int i0 = kq * 96;
        #pragma unroll 8
        for (int ii = 0; ii < 96; ++ii) p = fmaf(gs[i0 + ii], Wh1[kb * 49152 + (i0 + ii) * 128 + j], p);
        psum[kq][j] = p;
        __syncthreads();
        if (tid < HH) t1s[j] = geluf(bh1[kb * 128 + j] + psum[0][j] + psum[1][j] + psum[2][j] + psum[3][j]);
        __syncthreads();
        if (tid < 256) {
            int o = tid & 63, sc = tid >> 6;
            float p2 = 0.0f;
            int i0b = sc * 32;
            #pragma unroll 8
            for (int ii = 0; ii < 32; ++ii) p2 = fmaf(t1s[i0b + ii], Wh2[kb * 8192 + (i0b + ii) * 64 + o], p2);
            psum[sc][o] = p2;
        }
        __syncthreads();
        if (tid < 64) t2s[tid] = geluf(bh2[kb * 64 + tid] + psum[0][tid] + psum[1][tid] + psum[2][tid] + psum[3][tid]);
        __syncthreads();
        if (tid < 64) {
            float v = t2s[tid] * Wh3[kb * 64 + tid];
            #pragma unroll
            for (int m = 32; m > 0; m >>= 1) v += __shfl_xor(v, m);
            if (tid == 0) {
                float acc = v + bh3[kb];
                float r;
                if (kb == 0)      r = softplusf(acc) + 1.0f;
                else if (kb == 1) r = 1.0f / (1.0f + expf(-acc));
                else              r = softplusf(acc);
                out[kb] = r;
            }
        }
    } else {
        float p = 0.0f;
        int i0 = kq * 96;
        #pragma unroll 8
        for (int ii = 0; ii < 96; ++ii) p = fmaf(gs[i0 + ii], We[(i0 + ii) * 128 + j], p);
        psum[kq][j] = p;
        __syncthreads();
        if (tid < HH) out[3 + j] = be[j] + psum[0][j] + psum[1][j] + psum[2][j] + psum[3][j];
    }
}

// ---------------- launch ----------------

extern "C" void kernel_launch(void* const* d_in, const int* in_sizes, int n_in,
                              void* d_out, int out_size, void* d_ws, size_t ws_size,
                              hipStream_t stream) {
    const float* x      = (const float*)d_in[0];
    const int*   hedges = (const int*)d_in[1];
    const float* Wi     = (const float*)d_in[2];
    const float* bi     = (const float*)d_in[3];
    const float* lnig   = (const float*)d_in[4];
    const float* lnib   = (const float*)d_in[5];
    const float* Wc     = (const float*)d_in[6];
    const float* bc     = (const float*)d_in[7];
    const float* Wq     = (const float*)d_in[8];
    const float* bq     = (const float*)d_in[9];
    const float* Wk     = (const float*)d_in[10];
    const float* bk     = (const float*)d_in[11];
    const float* Wv     = (const float*)d_in[12];
    const float* bv     = (const float*)d_in[13];
    const float* Wo     = (const float*)d_in[14];
    const float* bo     = (const float*)d_in[15];
    const float* n1g    = (const float*)d_in[16];
    const float* n1b    = (const float*)d_in[17];
    const float* n2g    = (const float*)d_in[18];
    const float* n2b    = (const float*)d_in[19];
    const float* Wf1    = (const float*)d_in[20];
    const float* bf1    = (const float*)d_in[21];
    const float* Wf2    = (const float*)d_in[22];
    const float* bf2    = (const float*)d_in[23];
    const float* Wh1    = (const float*)d_in[24];
    const float* bh1    = (const float*)d_in[25];
    const float* Wh2    = (const float*)d_in[26];
    const float* bh2    = (const float*)d_in[27];
    const float* Wh3    = (const float*)d_in[28];
    const float* bh3    = (const float*)d_in[29];
    const float* We     = (const float*)d_in[30];
    const float* be     = (const float*)d_in[31];

    float* ws = (float*)d_ws;
    float* h    = ws;                          // 25600
    float* h1   = ws + 25600;                  // 25600
    float* hc   = ws + 51200;                  // 25600
    float* Q    = ws + 76800;                  // 25600
    float* K    = ws + 102400;                 // 25600
    float* V    = ws + 128000;                 // 25600
    float* Gf   = ws + 153600;                 // 40000
    unsigned long long* bmT = (unsigned long long*)(ws + 193600);  // 51200 u64
    int*   lst  = (int*)(ws + 296000);         // 200*1024 ints
    int*   cntA = (int*)(ws + 500800);         // 256 ints
    unsigned short* bw = (unsigned short*)(ws + 501056);           // 1277952 ushorts

    hipMemsetAsync(bmT, 0, (size_t)W64 * NN * sizeof(unsigned long long), stream);
    k_bitmapEmbed<<<512, 256, 0, stream>>>(hedges, bmT, x, Wi, bi, lnig, lnib,
                                           Wc, Wq, Wk, Wv, Wo, Wf1, Wf2, bw, h, hc);
    k_prep<<<NN, 1024, 0, stream>>>(bmT, Gf, lst, cntA);

    for (int l = 0; l < LL; ++l) {
        k_node1<<<NN, 1024, 0, stream>>>(h, hc, Gf, cntA,
            bc + l * HH,
            bw + OWQ + l * HH * HH, bq + l * HH,
            bw + OWK + l * HH * HH, bk + l * HH,
            bw + OWV + l * HH * HH, bv + l * HH,
            n1g + l * HH, n1b + l * HH,
            h1, Q, K, V);
        const unsigned short* bWcN = (l + 1 < LL) ? (bw + OWC + (l + 1) * HH * HH) : nullptr;
        k_edgefused<<<NN, 1024, 0, stream>>>(Q, K, V, hedges, lst, cntA, h1,
            bw + OWO + l * HH * HH, bo + l * HH,
            bw + OWF1 + l * HH * FFD, bf1 + l * FFD,
            bw + OWF2 + l * FFD * HH, bf2 + l * HH,
            n2g + l * HH, n2b + l * HH,
            bWcN, h, hc);
    }

    k_final4<<<4, 512, 0, stream>>>(h, Wh1, bh1, Wh2, bh2, Wh3, bh3, We, be, (float*)d_out);
}

// Round 13
// 187.851 us; speedup vs baseline: 2.2218x; 1.1410x over previous
//
#include <hip/hip_runtime.h>
#include <hip/hip_bf16.h>
#include <math.h>

#define NN 200
#define DD 8
#define HH 128
#define NHEAD 4
#define HDIM 32
#define LL 6
#define EE 16384
#define SS 8
#define FFD 512
#define W64 256                  // EE/64 bitmap words per node column

#define WSCALE 1048576.0f        // 2^20 fixed-point scale for LDS int attention atomics
#define WNORM  (1.0f/1048576.0f)
#define RSCALE 0.17677669529663687f   // 1/sqrt(32)

// ---------------- helpers ----------------

__device__ __forceinline__ float geluf(float x) {
    return 0.5f * x * (1.0f + erff(x * 0.70710678118654752f));
}
__device__ __forceinline__ float softplusf(float x) {
    return (x > 20.0f) ? x : log1pf(expf(x));
}
__device__ __forceinline__ void ln_reduce(const float* sv, const float* sv2, float* mred, int tid) {
    if (tid < 64) {
        float s1 = sv[tid] + sv[tid + 64];
        float s2 = sv2[tid] + sv2[tid + 64];
        #pragma unroll
        for (int m = 32; m > 0; m >>= 1) {
            s1 += __shfl_xor(s1, m);
            s2 += __shfl_xor(s2, m);
        }
        if (tid == 0) { mred[0] = s1 * (1.0f / HH); mred[1] = s2 * (1.0f / HH); }
    }
}

// ---------------- setup ----------------

// bitmap scatter (all 512 blocks) + embed h0/hc0 (blocks < 200)
__launch_bounds__(256)
__global__ void k_bitmapEmbed(const int* __restrict__ hedges, unsigned long long* __restrict__ bmT,
                              const float* __restrict__ x, const float* __restrict__ Wi,
                              const float* __restrict__ bi, const float* __restrict__ lnig,
                              const float* __restrict__ lnib, const float* __restrict__ Wc0,
                              float* __restrict__ h, float* __restrict__ hc) {
    int a = blockIdx.x, tid = threadIdx.x;
    // scatter this block's slice of memberships
    {
        int t = a * 256 + tid;
        int n = hedges[t];
        int e = t >> 3;
        atomicOr(&bmT[(e >> 6) * NN + n], 1ULL << (e & 63));
    }
    if (a >= NN) return;
    __shared__ float row[HH], sv[HH], sv2[HH], mred[2];
    __shared__ float psum[2][HH];
    float s = 0.0f;
    if (tid < HH) {
        s = bi[tid];
        #pragma unroll
        for (int d = 0; d < DD; ++d) s = fmaf(x[a * DD + d], Wi[d * HH + tid], s);
        sv[tid] = s; sv2[tid] = s * s;
    }
    __syncthreads();
    ln_reduce(sv, sv2, mred, tid);
    __syncthreads();
    if (tid < HH) {
        float mean = mred[0], var = mred[1] - mean * mean;
        float v = (s - mean) * rsqrtf(var + 1e-5f) * lnig[tid] + lnib[tid];
        float ge = geluf(v);
        int i2 = (tid >> 1) * 2;
        float div = expf((float)i2 * (-9.210340371976184f / 128.0f));
        float ang = (float)a * div;
        float pe = (tid & 1) ? cosf(ang) : sinf(ang);
        float hv = ge + pe;
        row[tid] = hv;
        h[a * HH + tid] = hv;
    }
    __syncthreads();
    {   // hc0 = row @ Wc0: 256 threads, 2-way split-K
        int kf = tid >> 7, j = tid & 127, k0 = kf * 64;
        float acc = 0.0f;
        #pragma unroll 8
        for (int kk = 0; kk < 64; ++kk) acc = fmaf(row[k0 + kk], Wc0[(k0 + kk) * HH + j], acc);
        psum[kf][j] = acc;
    }
    __syncthreads();
    if (tid < HH) hc[a * HH + tid] = psum[0][tid] + psum[1][tid];
}

// Per node a: float G row + member-edge list + count
__launch_bounds__(1024)
__global__ void k_prep(const unsigned long long* __restrict__ bmT,
                       float* __restrict__ Gf, int* __restrict__ lst, int* __restrict__ cntA) {
    __shared__ unsigned long long colA[W64];
    __shared__ int psG[4][256];
    __shared__ int wsum[4];
    int a = blockIdx.x, tid = threadIdx.x;
    if (tid < W64) colA[tid] = bmT[tid * NN + a];
    __syncthreads();
    {   // G row popcount, 4-way word split
        int q = tid >> 8, b = tid & 255;
        if (b < NN) {
            int acc = 0, w0 = q * 64;
            #pragma unroll 8
            for (int w = 0; w < 64; ++w) acc += __popcll(colA[w0 + w] & bmT[(w0 + w) * NN + b]);
            psG[q][b] = acc;
        }
    }
    // list extraction prefix-scan on first 256 threads
    unsigned long long w = 0ULL; int c = 0, incl = 0, lane = tid & 63, wid = tid >> 6;
    if (tid < W64) {
        w = colA[tid];
        c = __popcll(w);
        incl = c;
        #pragma unroll
        for (int m = 1; m < 64; m <<= 1) {
            int v = __shfl_up(incl, m);
            if (lane >= m) incl += v;
        }
        if (lane == 63) wsum[wid] = incl;
    }
    __syncthreads();
    if (tid == 0) {
        int ss = 0;
        #pragma unroll
        for (int i = 0; i < 4; ++i) { int v = wsum[i]; wsum[i] = ss; ss += v; }
        cntA[a] = ss;
    }
    if (tid < NN) Gf[a * NN + tid] = (float)(psG[0][tid] + psG[1][tid] + psG[2][tid] + psG[3][tid]);
    __syncthreads();
    if (tid < W64) {
        int base = wsum[wid] + incl - c;
        while (w) {
            int b = __ffsll((long long)w) - 1;
            w &= w - 1;
            lst[a * 1024 + base++] = tid * 64 + b;
        }
    }
}

// ---------------- layer kernels ----------------

// conv(G@hc) + LN1 + QKV.  grid: 200 x 1024, wide scalar phases + register prefetch
__launch_bounds__(1024)
__global__ void k_node1(const float* __restrict__ h, const float* __restrict__ hc,
                        const float* __restrict__ Gf, const int* __restrict__ cntA,
                        const float* __restrict__ bc,
                        const float* __restrict__ Wq, const float* __restrict__ bq,
                        const float* __restrict__ Wk, const float* __restrict__ bk,
                        const float* __restrict__ Wv, const float* __restrict__ bv,
                        const float* __restrict__ n1g, const float* __restrict__ n1b,
                        float* __restrict__ h1, float* __restrict__ Qo,
                        float* __restrict__ Ko, float* __restrict__ Vo) {
    int n = blockIdx.x, tid = threadIdx.x;
    int j = tid & 127, kq = tid >> 7;
    __shared__ float Gs[NN];
    __shared__ float row[HH], sv[HH], sv2[HH], mred[2];
    __shared__ float psA[8][HH], psB[8][HH], psC[8][HH];

    // ---- register prefetch (issue all independent loads up front)
    float hcv[25];
    {
        int m0 = kq * 25;
        #pragma unroll
        for (int mm = 0; mm < 25; ++mm) hcv[mm] = hc[(m0 + mm) * HH + j];
    }
    float hval = 0.0f, bcv = 0.0f, g1 = 0.0f, b1 = 0.0f;
    if (tid < HH) { hval = h[n * HH + tid]; bcv = bc[tid]; g1 = n1g[tid]; b1 = n1b[tid]; }
    float biasv = 0.0f;
    if (tid < 384) {
        int wh = tid >> 7;
        biasv = (wh == 0) ? bq[j] : (wh == 1) ? bk[j] : bv[j];
    }
    float cntn = fmaxf((float)cntA[n], 1.0f);
    if (tid < NN) Gs[tid] = Gf[n * NN + tid];
    __syncthreads();

    // conv: 8 kq x 25 rows, pure FMA from regs + LDS broadcast
    {
        float p = 0.0f; int m0 = kq * 25;
        #pragma unroll
        for (int mm = 0; mm < 25; ++mm) p = fmaf(Gs[m0 + mm], hcv[mm], p);
        psA[kq][j] = p;
    }
    __syncthreads();
    float val = 0.0f;
    if (tid < HH) {
        float acc = psA[0][tid] + psA[1][tid] + psA[2][tid] + psA[3][tid]
                  + psA[4][tid] + psA[5][tid] + psA[6][tid] + psA[7][tid];
        val = hval + acc / (8.0f * cntn) + bcv;
        sv[tid] = val; sv2[tid] = val * val;
    }
    __syncthreads();
    ln_reduce(sv, sv2, mred, tid);
    __syncthreads();
    if (tid < HH) {
        float mean = mred[0], var = mred[1] - mean * mean;
        float hv = (val - mean) * rsqrtf(var + 1e-5f) * g1 + b1;
        row[tid] = hv;
        h1[n * HH + tid] = hv;
    }
    __syncthreads();
    // QKV: 8 kq x 16 k, 3 accumulators
    {
        float pq = 0.0f, pk = 0.0f, pv = 0.0f; int k0 = kq * 16;
        #pragma unroll 4
        for (int kk = 0; kk < 16; ++kk) {
            float r = row[k0 + kk]; int idx = (k0 + kk) * HH + j;
            pq = fmaf(r, Wq[idx], pq);
            pk = fmaf(r, Wk[idx], pk);
            pv = fmaf(r, Wv[idx], pv);
        }
        psA[kq][j] = pq; psB[kq][j] = pk; psC[kq][j] = pv;
    }
    __syncthreads();
    if (tid < 384) {
        int wh = tid >> 7;
        const float (*pf)[HH] = (wh == 0) ? psA : (wh == 1) ? psB : psC;
        float acc = pf[0][j] + pf[1][j] + pf[2][j] + pf[3][j]
                  + pf[4][j] + pf[5][j] + pf[6][j] + pf[7][j];
        float o = biasv + acc;
        if (wh == 0)      Qo[n * HH + j] = o;
        else if (wh == 1) Ko[n * HH + j] = o;
        else              Vo[n * HH + j] = o;
    }
}

// attention + Wo + FFN + LN2 + next-layer hc.  grid: 200 x 1024
__launch_bounds__(1024)
__global__ void k_edgefused(const float* __restrict__ Q, const float* __restrict__ K,
                            const float* __restrict__ V, const int* __restrict__ hedges,
                            const int* __restrict__ lst, const int* __restrict__ cntA,
                            const float* __restrict__ h1,
                            const float* __restrict__ Wo, const float* __restrict__ bo,
                            const float* __restrict__ Wf1, const float* __restrict__ bf1,
                            const float* __restrict__ Wf2, const float* __restrict__ bf2,
                            const float* __restrict__ n2g, const float* __restrict__ n2b,
                            const float* __restrict__ WcN,
                            float* __restrict__ h, float* __restrict__ hc) {
    __shared__ float Ts[NHEAD * NN];
    __shared__ int   Wrow[NHEAD * NN];
    __shared__ float Qs[HH];
    __shared__ float psum[8][HH];
    __shared__ float psF[2][FFD];
    __shared__ float ts[FFD];
    __shared__ float sv[HH], sv2[HH], mred[2];
    __shared__ float aggs[HH], h2s[HH], rowN[HH];

    int a = blockIdx.x, tid = threadIdx.x;
    int j = tid & 127, kq = tid >> 7;
    int cnt = cntA[a];
    float cntn = fmaxf((float)cnt, 1.0f);
    int ntask = cnt * NHEAD;
    const int* lstA = lst + a * 1024;

    // ---- register prefetch
    float h1v = 0.0f, bov = 0.0f, bf2v = 0.0f, n2gv = 0.0f, n2bv = 0.0f;
    if (tid < HH) {
        h1v = h1[a * HH + tid]; bov = bo[tid];
        bf2v = bf2[tid]; n2gv = n2g[tid]; n2bv = n2b[tid];
    }
    float bf1v = 0.0f;
    if (tid < FFD) bf1v = bf1[tid];
    // member-edge chains for up to 4 strip-mine iterations
    int4 pe0[4], pe1[4];
    #pragma unroll
    for (int it = 0; it < 4; ++it) {
        int t = tid + it * 1024;
        pe0[it] = make_int4(0, 0, 0, 0); pe1[it] = make_int4(0, 0, 0, 0);
        if (t < ntask) {
            int e = lstA[t >> 2];
            pe0[it] = ((const int4*)hedges)[e * 2];
            pe1[it] = ((const int4*)hedges)[e * 2 + 1];
        }
    }
    // K row for logits (independent of Qs)
    int lb = tid & 255, lh = tid >> 8;
    float4 kv[8];
    if (lb < NN) {
        const float4* kp4 = (const float4*)(K + lb * HH + lh * HDIM);
        #pragma unroll
        for (int u = 0; u < 8; ++u) kv[u] = kp4[u];
    }
    if (tid < HH) Qs[tid] = Q[a * HH + tid];
    if (tid < NHEAD * NN) Wrow[tid] = 0;
    __syncthreads();

    // logits Ts[h][b] = (q_a[h].k_b[h]) * RSCALE
    if (lb < NN) {
        const float4* qp4 = (const float4*)(Qs + lh * HDIM);
        float acc = 0.0f;
        #pragma unroll
        for (int u = 0; u < 8; ++u) {
            float4 qv = qp4[u];
            acc += qv.x * kv[u].x + qv.y * kv[u].y + qv.z * kv[u].z + qv.w * kv[u].w;
        }
        Ts[lh * NN + lb] = acc * RSCALE;
    }
    __syncthreads();

    // phase A: per (member-edge, head) softmax -> LDS int scatter
    #pragma unroll
    for (int it = 0; it < 4; ++it) {
        int t = tid + it * 1024;
        if (t < ntask) {
            int hh = t & 3;
            int4 e0 = pe0[it], e1 = pe1[it];
            const float* Tr = Ts + hh * NN;
            float l0 = Tr[e0.x], l1 = Tr[e0.y], l2 = Tr[e0.z], l3 = Tr[e0.w];
            float l4 = Tr[e1.x], l5 = Tr[e1.y], l6 = Tr[e1.z], l7 = Tr[e1.w];
            float mx = fmaxf(fmaxf(fmaxf(l0, l1), fmaxf(l2, l3)),
                             fmaxf(fmaxf(l4, l5), fmaxf(l6, l7)));
            l0 = __expf(l0 - mx); l1 = __expf(l1 - mx); l2 = __expf(l2 - mx); l3 = __expf(l3 - mx);
            l4 = __expf(l4 - mx); l5 = __expf(l5 - mx); l6 = __expf(l6 - mx); l7 = __expf(l7 - mx);
            float inv = WSCALE / (l0 + l1 + l2 + l3 + l4 + l5 + l6 + l7);
            int* Wr = Wrow + hh * NN;
            atomicAdd(&Wr[e0.x], __float2int_rn(l0 * inv));
            atomicAdd(&Wr[e0.y], __float2int_rn(l1 * inv));
            atomicAdd(&Wr[e0.z], __float2int_rn(l2 * inv));
            atomicAdd(&Wr[e0.w], __float2int_rn(l3 * inv));
            atomicAdd(&Wr[e1.x], __float2int_rn(l4 * inv));
            atomicAdd(&Wr[e1.y], __float2int_rn(l5 * inv));
            atomicAdd(&Wr[e1.z], __float2int_rn(l6 * inv));
            atomicAdd(&Wr[e1.w], __float2int_rn(l7 * inv));
        }
    }
    __syncthreads();

    // phase B: agg = Wrow@V, 8 kq x 25 b  (j = hh*32+d)
    {
        int hh = (tid >> 5) & 3;
        float acc = 0.0f; int b0 = kq * 25;
        #pragma unroll 5
        for (int bb = 0; bb < 25; ++bb) {
            int b = b0 + bb;
            acc = fmaf((float)Wrow[hh * NN + b], V[b * HH + j], acc);
        }
        psum[kq][j] = acc;
    }
    __syncthreads();
    if (tid < HH) {
        float acc = psum[0][tid] + psum[1][tid] + psum[2][tid] + psum[3][tid]
                  + psum[4][tid] + psum[5][tid] + psum[6][tid] + psum[7][tid];
        aggs[tid] = acc * WNORM / cntn;
    }
    __syncthreads();
    // Wo GEMV: 8 kq x 16
    {
        float p = 0.0f; int k0 = kq * 16;
        #pragma unroll 8
        for (int kk = 0; kk < 16; ++kk) p = fmaf(aggs[k0 + kk], Wo[(k0 + kk) * HH + j], p);
        psum[kq][j] = p;
    }
    __syncthreads();
    if (tid < HH) {
        float acc = psum[0][tid] + psum[1][tid] + psum[2][tid] + psum[3][tid]
                  + psum[4][tid] + psum[5][tid] + psum[6][tid] + psum[7][tid];
        h2s[tid] = h1v + bov + acc;
    }
    __syncthreads();
    // FFN1: 512 outputs x 2-way split-K (chain 64)
    {
        int f = tid & 511, hf = tid >> 9;
        float tval = 0.0f; int k0 = hf * 64;
        #pragma unroll 8
        for (int kk = 0; kk < 64; ++kk) tval = fmaf(h2s[k0 + kk], Wf1[(k0 + kk) * FFD + f], tval);
        psF[hf][f] = tval;
    }
    __syncthreads();
    if (tid < FFD) ts[tid] = geluf(bf1v + psF[0][tid] + psF[1][tid]);
    __syncthreads();
    // FFN2: 8 kq x 64
    {
        float p = 0.0f; int f0 = kq * 64;
        #pragma unroll 8
        for (int ff = 0; ff < 64; ++ff) p = fmaf(ts[f0 + ff], Wf2[(f0 + ff) * HH + j], p);
        psum[kq][j] = p;
    }
    __syncthreads();
    float o = 0.0f;
    if (tid < HH) {
        float acc = psum[0][tid] + psum[1][tid] + psum[2][tid] + psum[3][tid]
                  + psum[4][tid] + psum[5][tid] + psum[6][tid] + psum[7][tid];
        o = h2s[tid] + bf2v + acc;
        sv[tid] = o; sv2[tid] = o * o;
    }
    __syncthreads();
    ln_reduce(sv, sv2, mred, tid);
    __syncthreads();
    if (tid < HH) {
        float mean = mred[0], var = mred[1] - mean * mean;
        float hv = (o - mean) * rsqrtf(var + 1e-5f) * n2gv + n2bv;
        rowN[tid] = hv;
        h[a * HH + tid] = hv;
    }
    __syncthreads();
    if (WcN) {
        float p = 0.0f; int k0 = kq * 16;
        #pragma unroll 8
        for (int kk = 0; kk < 16; ++kk) p = fmaf(rowN[k0 + kk], WcN[(k0 + kk) * HH + j], p);
        psum[kq][j] = p;
        __syncthreads();
        if (tid < HH) {
            float acc = psum[0][tid] + psum[1][tid] + psum[2][tid] + psum[3][tid]
                      + psum[4][tid] + psum[5][tid] + psum[6][tid] + psum[7][tid];
            hc[a * HH + tid] = acc;
        }
    }
}

// Pool + heads + emb, 4 blocks x 512
__launch_bounds__(512)
__global__ void k_final4(const float* __restrict__ h,
                         const float* __restrict__ Wh1, const float* __restrict__ bh1,
                         const float* __restrict__ Wh2, const float* __restrict__ bh2,
                         const float* __restrict__ Wh3, const float* __restrict__ bh3,
                         const float* __restrict__ We, const float* __restrict__ be,
                         float* __restrict__ out) {
    __shared__ float gs[384];
    __shared__ float pm[4][HH], px[4][HH];
    __shared__ float psum[4][HH];
    __shared__ float t1s[HH];
    __shared__ float t2s[64];
    int tid = threadIdx.x, j = tid & 127, kq = tid >> 7, kb = blockIdx.x;
    {
        float sm = 0.0f, mx = -3.4e38f;
        for (int r = 0; r < 50; ++r) {
            float v = h[(kq * 50 + r) * HH + j];
            sm += v; mx = fmaxf(mx, v);
        }
        pm[kq][j] = sm; px[kq][j] = mx;
    }
    __syncthreads();
    if (tid < HH) {
        float s = pm[0][j] + pm[1][j] + pm[2][j] + pm[3][j];
        float m = fmaxf(fmaxf(px[0][j], px[1][j]), fmaxf(px[2][j], px[3][j]));
        gs[j] = s * (1.0f / NN); gs[HH + j] = m; gs[2 * HH + j] = s;
    }
    __syncthreads();
    if (kb < 3) {
        float p = 0.0f;
        int i0 = kq * 96;
        #pragma unroll 8
        for (int ii = 0; ii < 96; ++ii) p = fmaf(gs[i0 + ii], Wh1[kb * 49152 + (i0 + ii) * 128 + j], p);
        psum[kq][j] = p;
        __syncthreads();
        if (tid < HH) t1s[j] = geluf(bh1[kb * 128 + j] + psum[0][j] + psum[1][j] + psum[2][j] + psum[3][j]);
        __syncthreads();
        if (tid < 256) {
            int o = tid & 63, sc = tid >> 6;
            float p2 = 0.0f;
            int i0b = sc * 32;
            #pragma unroll 8
            for (int ii = 0; ii < 32; ++ii) p2 = fmaf(t1s[i0b + ii], Wh2[kb * 8192 + (i0b + ii) * 64 + o], p2);
            psum[sc][o] = p2;
        }
        __syncthreads();
        if (tid < 64) t2s[tid] = geluf(bh2[kb * 64 + tid] + psum[0][tid] + psum[1][tid] + psum[2][tid] + psum[3][tid]);
        __syncthreads();
        if (tid < 64) {
            float v = t2s[tid] * Wh3[kb * 64 + tid];
            #pragma unroll
            for (int m = 32; m > 0; m >>= 1) v += __shfl_xor(v, m);
            if (tid == 0) {
                float acc = v + bh3[kb];
                float r;
                if (kb == 0)      r = softplusf(acc) + 1.0f;
                else if (kb == 1) r = 1.0f / (1.0f + expf(-acc));
                else              r = softplusf(acc);
                out[kb] = r;
            }
        }
    } else {
        float p = 0.0f;
        int i0 = kq * 96;
        #pragma unroll 8
        for (int ii = 0; ii < 96; ++ii) p = fmaf(gs[i0 + ii], We[(i0 + ii) * 128 + j], p);
        psum[kq][j] = p;
        __syncthreads();
        if (tid < HH) out[3 + j] = be[j] + psum[0][j] + psum[1][j] + psum[2][j] + psum[3][j];
    }
}

// ---------------- launch ----------------

extern "C" void kernel_launch(void* const* d_in, const int* in_sizes, int n_in,
                              void* d_out, int out_size, void* d_ws, size_t ws_size,
                              hipStream_t stream) {
    const float* x      = (const float*)d_in[0];
    const int*   hedges = (const int*)d_in[1];
    const float* Wi     = (const float*)d_in[2];
    const float* bi     = (const float*)d_in[3];
    const float* lnig   = (const float*)d_in[4];
    const float* lnib   = (const float*)d_in[5];
    const float* Wc     = (const float*)d_in[6];
    const float* bc     = (const float*)d_in[7];
    const float* Wq     = (const float*)d_in[8];
    const float* bq     = (const float*)d_in[9];
    const float* Wk     = (const float*)d_in[10];
    const float* bk     = (const float*)d_in[11];
    const float* Wv     = (const float*)d_in[12];
    const float* bv     = (const float*)d_in[13];
    const float* Wo     = (const float*)d_in[14];
    const float* bo     = (const float*)d_in[15];
    const float* n1g    = (const float*)d_in[16];
    const float* n1b    = (const float*)d_in[17];
    const float* n2g    = (const float*)d_in[18];
    const float* n2b    = (const float*)d_in[19];
    const float* Wf1    = (const float*)d_in[20];
    const float* bf1    = (const float*)d_in[21];
    const float* Wf2    = (const float*)d_in[22];
    const float* bf2    = (const float*)d_in[23];
    const float* Wh1    = (const float*)d_in[24];
    const float* bh1    = (const float*)d_in[25];
    const float* Wh2    = (const float*)d_in[26];
    const float* bh2    = (const float*)d_in[27];
    const float* Wh3    = (const float*)d_in[28];
    const float* bh3    = (const float*)d_in[29];
    const float* We     = (const float*)d_in[30];
    const float* be     = (const float*)d_in[31];

    float* ws = (float*)d_ws;
    float* h    = ws;                          // 25600
    float* h1   = ws + 25600;                  // 25600
    float* hc   = ws + 51200;                  // 25600
    float* Q    = ws + 76800;                  // 25600
    float* K    = ws + 102400;                 // 25600
    float* V    = ws + 128000;                 // 25600
    float* Gf   = ws + 153600;                 // 40000
    unsigned long long* bmT = (unsigned long long*)(ws + 193600);  // 51200 u64
    int*   lst  = (int*)(ws + 296000);         // 200*1024 ints
    int*   cntA = (int*)(ws + 500800);         // 256 ints

    hipMemsetAsync(bmT, 0, (size_t)W64 * NN * sizeof(unsigned long long), stream);
    k_bitmapEmbed<<<512, 256, 0, stream>>>(hedges, bmT, x, Wi, bi, lnig, lnib, Wc, h, hc);
    k_prep<<<NN, 1024, 0, stream>>>(bmT, Gf, lst, cntA);

    for (int l = 0; l < LL; ++l) {
        k_node1<<<NN, 1024, 0, stream>>>(h, hc, Gf, cntA,
            bc + l * HH,
            Wq + l * HH * HH, bq + l * HH,
            Wk + l * HH * HH, bk + l * HH,
            Wv + l * HH * HH, bv + l * HH,
            n1g + l * HH, n1b + l * HH,
            h1, Q, K, V);
        const float* WcN = (l + 1 < LL) ? (Wc + (l + 1) * HH * HH) : nullptr;
        k_edgefused<<<NN, 1024, 0, stream>>>(Q, K, V, hedges, lst, cntA, h1,
            Wo + l * HH * HH, bo + l * HH,
            Wf1 + l * HH * FFD, bf1 + l * FFD,
            Wf2 + l * FFD * HH, bf2 + l * HH,
            n2g + l * HH, n2b + l * HH,
            WcN, h, hc);
    }

    k_final4<<<4, 512, 0, stream>>>(h, Wh1, bh1, Wh2, bh2, Wh3, bh3, We, be, (float*)d_out);
}